// Round 8
// baseline (1451.495 us; speedup 1.0000x reference)
//
#include <hip/hip_runtime.h>
#include <hip/hip_cooperative_groups.h>

namespace cg = cooperative_groups;

namespace {

constexpr int NN = 50000;   // nodes
constexpr int NE = 800000;  // edges
constexpr int NB = 64;      // graphs / batch
constexpr int NL = 32;      // path length
constexpr int ND = 256;     // D == H == 256
constexpr int NSCAN = 196;  // ceil(50176/256) scan blocks

typedef __attribute__((ext_vector_type(8))) short short8v;  // 8 bf16 (4 VGPRs)
typedef __attribute__((ext_vector_type(4))) float float4v;  // MFMA accumulator

__device__ __forceinline__ float sigf(float x){ return 1.0f/(1.0f + __expf(-x)); }

// split 8 fp32 -> 8 bf16-hi (truncated; exact bits) + 8 bf16-lo (of remainder)
__device__ __forceinline__ void split8(float4 fa, float4 fb, uint4& h, uint4& lo){
  uint a0=__float_as_uint(fa.x), a1=__float_as_uint(fa.y), a2=__float_as_uint(fa.z), a3=__float_as_uint(fa.w);
  uint b0=__float_as_uint(fb.x), b1=__float_as_uint(fb.y), b2=__float_as_uint(fb.z), b3=__float_as_uint(fb.w);
  h.x = (a0>>16) | (a1 & 0xFFFF0000u);
  h.y = (a2>>16) | (a3 & 0xFFFF0000u);
  h.z = (b0>>16) | (b1 & 0xFFFF0000u);
  h.w = (b2>>16) | (b3 & 0xFFFF0000u);
  float r0 = fa.x - __uint_as_float(a0 & 0xFFFF0000u);
  float r1 = fa.y - __uint_as_float(a1 & 0xFFFF0000u);
  float r2 = fa.z - __uint_as_float(a2 & 0xFFFF0000u);
  float r3 = fa.w - __uint_as_float(a3 & 0xFFFF0000u);
  float r4 = fb.x - __uint_as_float(b0 & 0xFFFF0000u);
  float r5 = fb.y - __uint_as_float(b1 & 0xFFFF0000u);
  float r6 = fb.z - __uint_as_float(b2 & 0xFFFF0000u);
  float r7 = fb.w - __uint_as_float(b3 & 0xFFFF0000u);
  lo.x = (__float_as_uint(r0)>>16) | (__float_as_uint(r1) & 0xFFFF0000u);
  lo.y = (__float_as_uint(r2)>>16) | (__float_as_uint(r3) & 0xFFFF0000u);
  lo.z = (__float_as_uint(r4)>>16) | (__float_as_uint(r5) & 0xFFFF0000u);
  lo.w = (__float_as_uint(r6)>>16) | (__float_as_uint(r7) & 0xFFFF0000u);
}

// ================= CSR build (counting sort of edges by dst) =================
__global__ void k_hist(const int* __restrict__ dst, int* __restrict__ cnt){
  int stride = gridDim.x * blockDim.x;
  for (int e = blockIdx.x*blockDim.x + threadIdx.x; e < NE; e += stride)
    atomicAdd(&cnt[dst[e]], 1);
}

__global__ void k_scan_block(const int* __restrict__ cnt, int* __restrict__ offs,
                             int* __restrict__ bsum){
  __shared__ int s[256];
  const int t = threadIdx.x, i = blockIdx.x*256 + t;
  int v = cnt[i];
  s[t] = v; __syncthreads();
  #pragma unroll
  for (int off = 1; off < 256; off <<= 1){
    int x = (t >= off) ? s[t-off] : 0;
    __syncthreads();
    s[t] += x;
    __syncthreads();
  }
  offs[i] = s[t] - v;
  if (t == 255) bsum[blockIdx.x] = s[255];
}

__global__ void k_scan_top(const int* __restrict__ bsum, int* __restrict__ bsum2){
  __shared__ int s[256];
  const int t = threadIdx.x;
  int v = (t < NSCAN) ? bsum[t] : 0;
  s[t] = v; __syncthreads();
  #pragma unroll
  for (int off = 1; off < 256; off <<= 1){
    int x = (t >= off) ? s[t-off] : 0;
    __syncthreads();
    s[t] += x;
    __syncthreads();
  }
  if (t < NSCAN) bsum2[t] = s[t] - v;
}

__global__ void k_scan_add(int* __restrict__ offs, const int* __restrict__ bsum2,
                           int* __restrict__ cursor){
  const int i = blockIdx.x*256 + threadIdx.x;
  int v = offs[i] + bsum2[blockIdx.x];
  offs[i] = v;
  cursor[i] = v;
}

__global__ void k_fill(const int* __restrict__ src, const int* __restrict__ dst,
                       int* __restrict__ cursor, int* __restrict__ csr){
  int stride = gridDim.x * blockDim.x;
  for (int e = blockIdx.x*blockDim.x + threadIdx.x; e < NE; e += stride){
    int d = dst[e];
    int pos = atomicAdd(&cursor[d], 1);
    csr[pos] = src[e];
  }
}

// ================= mean-aggregate gather: one block per dst node =================
__launch_bounds__(256, 8)
__global__ void k_gather(const float* __restrict__ feat, const int* __restrict__ offs,
                         const int* __restrict__ csr, float* __restrict__ out){
  __shared__ float4 sp[256];
  const int u = blockIdx.x, t = threadIdx.x;
  const int w = t >> 6, l = t & 63;
  const int beg = offs[u], end = offs[u+1];
  const int lc = l * 4;
  float a0 = 0.f, a1 = 0.f, a2 = 0.f, a3 = 0.f;
  int e = beg + w;
  for (; e + 4 < end; e += 8){
    int s0 = csr[e], s1 = csr[e+4];
    const float4 v0 = *(const float4*)(feat + (long long)s0*ND + lc);
    const float4 v1 = *(const float4*)(feat + (long long)s1*ND + lc);
    a0 += v0.x + v1.x; a1 += v0.y + v1.y; a2 += v0.z + v1.z; a3 += v0.w + v1.w;
  }
  if (e < end){
    int s0 = csr[e];
    const float4 v0 = *(const float4*)(feat + (long long)s0*ND + lc);
    a0 += v0.x; a1 += v0.y; a2 += v0.z; a3 += v0.w;
  }
  sp[t] = make_float4(a0, a1, a2, a3);
  __syncthreads();
  if (t < 64){
    float4 p0 = sp[t], p1 = sp[64+t], p2 = sp[128+t], p3 = sp[192+t];
    float inv = 1.0f / fmaxf((float)(end - beg), 1.0f);
    float4 r;
    r.x = (p0.x + p1.x + p2.x + p3.x) * inv;
    r.y = (p0.y + p1.y + p2.y + p3.y) * inv;
    r.z = (p0.z + p1.z + p2.z + p3.z) * inv;
    r.w = (p0.w + p1.w + p2.w + p3.w) * inv;
    *(float4*)(out + (long long)u*ND + t*4) = r;
  }
}

// ============ weight prep: fragment-linear swizzled [wl; wr] bf16 hi/lo ============
__global__ void k_wsplit(const float* __restrict__ wl, const float* __restrict__ wr,
                         ushort* __restrict__ WtH, ushort* __restrict__ WtL){
  const int k = blockIdx.x;    // 0..511
  const int n = threadIdx.x;   // 0..255
  float v = (k < 256) ? wl[k*256 + n] : wr[(k-256)*256 + n];
  uint u = __float_as_uint(v);
  float r = v - __uint_as_float(u & 0xFFFF0000u);
  const int wc = n >> 6, nt = (n >> 4) & 3, lm = n & 15;
  const int kk = k >> 5, lq = (k >> 3) & 3, j = k & 7;
  const long long idx = (long long)(((wc*4 + nt)*16 + kk)*64 + lq*16 + lm)*8 + j;
  WtH[idx] = (ushort)(u >> 16);
  WtL[idx] = (ushort)(__float_as_uint(r) >> 16);
}

// ============ MFMA SAGE GEMM: barrier-free main loop + distance-1 prefetch ============
__launch_bounds__(256, 2)
__global__ void k_gemm_mfma(const float* __restrict__ A1, const float* __restrict__ A2,
                            const ushort* __restrict__ WtH, const ushort* __restrict__ WtL,
                            const float* __restrict__ bias, float* __restrict__ C, int relu)
{
  __shared__ float eb[16*260];     // epilogue staging (16.6 KB)
  const int t  = threadIdx.x;
  const int w  = t >> 6;           // wave 0..3
  const int l  = t & 63;           // lane
  const int lm = l & 15;
  const int lq = l >> 4;
  const int m0 = blockIdx.x * 64;

  const uint4* BH4 = (const uint4*)WtH;
  const uint4* BL4 = (const uint4*)WtL;

  const float4v vzero = {0.f, 0.f, 0.f, 0.f};
  float4v acc[4][4];
  #pragma unroll
  for (int i = 0; i < 4; ++i)
    #pragma unroll
    for (int j = 0; j < 4; ++j) acc[i][j] = vzero;

  long long arow[4];
  #pragma unroll
  for (int mt = 0; mt < 4; ++mt){
    int row = m0 + mt*16 + lm;
    row = (row < NN) ? row : (NN - 1);          // clamp: branchless, dup rows discarded later
    arow[mt] = (long long)row * ND;
  }
  int bbase[4];
  #pragma unroll
  for (int nt = 0; nt < 4; ++nt) bbase[nt] = (w*4 + nt)*1024 + l;

  auto ldB = [&](int kk, uint4* bh, uint4* bl){
    #pragma unroll
    for (int nt = 0; nt < 4; ++nt){
      int idx = bbase[nt] + kk*64;
      bh[nt] = BH4[idx];
      bl[nt] = BL4[idx];
    }
  };
  auto ldA = [&](int kk, uint4* ah, uint4* al){
    const float* Ab = (kk < 8) ? A1 : A2;       // constant-folds under full unroll
    const int koff = (kk & 7)*32 + lq*8;
    #pragma unroll
    for (int mt = 0; mt < 4; ++mt){
      const float* p = Ab + arow[mt] + koff;
      float4 fa = *(const float4*)p;
      float4 fb = *(const float4*)(p + 4);
      split8(fa, fb, ah[mt], al[mt]);
    }
  };

  uint4 bhb[2][4], blb[2][4], ahb[2][4], alb[2][4];
  ldB(0, bhb[0], blb[0]);
  ldA(0, ahb[0], alb[0]);

  #pragma unroll
  for (int kk = 0; kk < 16; ++kk){
    const int cur = kk & 1, nx = cur ^ 1;
    if (kk < 15){                               // constant under unroll
      ldB(kk + 1, bhb[nx], blb[nx]);
      ldA(kk + 1, ahb[nx], alb[nx]);
    }
    #pragma unroll
    for (int nt = 0; nt < 4; ++nt){
      short8v bh = *(short8v*)&bhb[cur][nt];
      short8v bl = *(short8v*)&blb[cur][nt];
      #pragma unroll
      for (int mt = 0; mt < 4; ++mt){
        short8v ah = *(short8v*)&ahb[cur][mt];
        short8v al = *(short8v*)&alb[cur][mt];
        acc[mt][nt] = __builtin_amdgcn_mfma_f32_16x16x32_bf16(ah, bh, acc[mt][nt], 0, 0, 0);
        acc[mt][nt] = __builtin_amdgcn_mfma_f32_16x16x32_bf16(al, bh, acc[mt][nt], 0, 0, 0);
        acc[mt][nt] = __builtin_amdgcn_mfma_f32_16x16x32_bf16(ah, bl, acc[mt][nt], 0, 0, 0);
      }
    }
  }

  // ---- epilogue: LDS transpose per 16-row slab, coalesced float4 stores ----
  float bvv[4];
  #pragma unroll
  for (int nt = 0; nt < 4; ++nt) bvv[nt] = bias[w*64 + nt*16 + lm];

  #pragma unroll
  for (int mt = 0; mt < 4; ++mt){
    #pragma unroll
    for (int nt = 0; nt < 4; ++nt){
      #pragma unroll
      for (int r = 0; r < 4; ++r){
        float v = acc[mt][nt][r] + bvv[nt];
        if (relu) v = fmaxf(v, 0.f);
        eb[(lq*4 + r)*260 + w*64 + nt*16 + lm] = v;   // C/D: col=lane&15, row=quad*4+reg
      }
    }
    __syncthreads();
    #pragma unroll
    for (int i = 0; i < 4; ++i){
      int idx = i*256 + t;           // 0..1023
      int rr  = idx >> 6;            // 0..15
      int c4  = (idx & 63) * 4;      // 0..252
      int grow = m0 + mt*16 + rr;
      if (grow < NN)
        *(float4*)(C + (long long)grow*ND + c4) = *(float4*)&eb[rr*260 + c4];
    }
    __syncthreads();
  }
}

// ---------------- LSTM input gates: Xg[i][g] = emb[paths[i]] . w_ih[g] + b_ih[g]+b_hh[g] ----------------
__launch_bounds__(256, 3)
__global__ void k_xgate(const float* __restrict__ emb, const int* __restrict__ paths,
                        const float* __restrict__ w_ih, const float* __restrict__ b_ih,
                        const float* __restrict__ b_hh, float* __restrict__ xg)
{
  __shared__ float As[16][68];
  __shared__ float Ws[16][260];
  const int t  = threadIdx.x;
  const int m0 = blockIdx.x * 64;    // path rows (2048 total)
  const int g0 = blockIdx.y * 256;   // gate cols (1024 total)
  const int rg = t >> 5, cg = t & 31;
  const int sm = t >> 2, sj = (t & 3) * 4;

  float acc[8][8];
  #pragma unroll
  for (int i = 0; i < 8; ++i)
    #pragma unroll
    for (int j = 0; j < 8; ++j) acc[i][j] = 0.f;

  const int node = paths[m0 + sm];
  const float* arow = emb  + (long long)node*ND;
  const float* wrow = w_ih + (long long)(g0 + t)*ND;

  for (int k0 = 0; k0 < 256; k0 += 16){
    float4 av = *(const float4*)(arow + k0 + sj);
    float4 q0 = *(const float4*)(wrow + k0 + 0);
    float4 q1 = *(const float4*)(wrow + k0 + 4);
    float4 q2 = *(const float4*)(wrow + k0 + 8);
    float4 q3 = *(const float4*)(wrow + k0 + 12);
    __syncthreads();
    As[sj+0][sm]=av.x; As[sj+1][sm]=av.y; As[sj+2][sm]=av.z; As[sj+3][sm]=av.w;
    Ws[ 0][t]=q0.x; Ws[ 1][t]=q0.y; Ws[ 2][t]=q0.z; Ws[ 3][t]=q0.w;
    Ws[ 4][t]=q1.x; Ws[ 5][t]=q1.y; Ws[ 6][t]=q1.z; Ws[ 7][t]=q1.w;
    Ws[ 8][t]=q2.x; Ws[ 9][t]=q2.y; Ws[10][t]=q2.z; Ws[11][t]=q2.w;
    Ws[12][t]=q3.x; Ws[13][t]=q3.y; Ws[14][t]=q3.z; Ws[15][t]=q3.w;
    __syncthreads();
    #pragma unroll
    for (int k = 0; k < 16; ++k){
      float a[8], b[8];
      *(float4*)&a[0] = *(const float4*)&As[k][rg*8];
      *(float4*)&a[4] = *(const float4*)&As[k][rg*8+4];
      *(float4*)&b[0] = *(const float4*)&Ws[k][cg*8];
      *(float4*)&b[4] = *(const float4*)&Ws[k][cg*8+4];
      #pragma unroll
      for (int i = 0; i < 8; ++i)
        #pragma unroll
        for (int j = 0; j < 8; ++j)
          acc[i][j] = fmaf(a[i], b[j], acc[i][j]);
    }
  }

  float bv[8];
  #pragma unroll
  for (int j = 0; j < 8; ++j){ int g = g0 + cg*8 + j; bv[j] = b_ih[g] + b_hh[g]; }
  #pragma unroll
  for (int i = 0; i < 8; ++i){
    int row = m0 + rg*8 + i;
    float o[8];
    #pragma unroll
    for (int j = 0; j < 8; ++j) o[j] = acc[i][j] + bv[j];
    *(float4*)(xg + (long long)row*1024 + g0 + cg*8 + 0) = *(float4*)&o[0];
    *(float4*)(xg + (long long)row*1024 + g0 + cg*8 + 4) = *(float4*)&o[4];
  }
}

// ---------------- cooperative persistent LSTM ----------------
// Grid 64 blocks x 256 threads (co-resident). Block b owns units u0=b*4..+4 ->
// 16 gate-cols j=gate*4+du (w_hh row gate*256+u0+du). w_hh slice is bf16-split ONCE
// into LDS in B-fragment layout. Per step: wave w computes G-tile for batches w*16..+16
// via mfma 16x16x32 (3-term split, K=256), h read from global bf16 hi/lo ping-pong.
// Lane owns (batch=w*16+(l&15), unit=u0+(l>>4)); c lives in a VGPR across all steps.
// xg prefetched one step ahead. One grid.sync per step (ping-pong h => race-free).
__launch_bounds__(256, 1)
__global__ void k_lstm(const float* __restrict__ xg, const float* __restrict__ w_hh,
                       ushort* __restrict__ hH, ushort* __restrict__ hL,
                       float* __restrict__ hfin)
{
  cg::grid_group grid = cg::this_grid();
  __shared__ ushort Bh[8*64*8];    // [kk][lane][8] (8 KB)
  __shared__ ushort Bl[8*64*8];
  __shared__ float  Gs[4*256];     // per-wave 16x16 gate tiles (4 KB)
  const int t  = threadIdx.x;
  const int w  = t >> 6, l = t & 63;
  const int b  = blockIdx.x;       // 0..63
  const int u0 = b*4;
  const int lm = l & 15, lq = l >> 4;
  const int m0w = w*16;

  // ---- one-time: stage block's 16 w_hh rows as bf16 hi/lo B-fragments ----
  #pragma unroll
  for (int i = 0; i < 16; ++i){
    int elem = i*256 + t;          // 0..4095
    int n = elem >> 8;             // col j 0..15 (gate = n>>2, du = n&3)
    int k = elem & 255;
    float v = w_hh[((n >> 2)*256 + u0 + (n & 3))*256 + k];
    uint uv = __float_as_uint(v);
    float r = v - __uint_as_float(uv & 0xFFFF0000u);
    int kk = k >> 5, lqq = (k >> 3) & 3, jj = k & 7;
    int pos = (kk*64 + lqq*16 + n)*8 + jj;
    Bh[pos] = (ushort)(uv >> 16);
    Bl[pos] = (ushort)(__float_as_uint(r) >> 16);
  }
  __syncthreads();

  const int mb = m0w + lm;         // owned batch row
  const int uu = u0 + lq;          // owned unit
  float c = 0.f;

  float xq[4];
  #pragma unroll
  for (int g = 0; g < 4; ++g) xq[g] = xg[(mb*NL + 0)*1024 + g*256 + uu];

  for (int ts = 0; ts < NL; ++ts){
    // prefetch next step's xg (independent of h -> hides under MFMA)
    const int tsn = (ts < NL-1) ? ts + 1 : ts;
    float xqn[4];
    #pragma unroll
    for (int g = 0; g < 4; ++g) xqn[g] = xg[(mb*NL + tsn)*1024 + g*256 + uu];

    if (ts > 0){
      const ushort* hHp = hH + ((ts-1) & 1)*16384;
      const ushort* hLp = hL + ((ts-1) & 1)*16384;
      float4v acc = {0.f, 0.f, 0.f, 0.f};
      #pragma unroll
      for (int kk = 0; kk < 8; ++kk){
        const int koff = kk*32 + lq*8;
        short8v ah = *(const short8v*)(hHp + mb*256 + koff);
        short8v al = *(const short8v*)(hLp + mb*256 + koff);
        short8v bh = *(const short8v*)&Bh[(kk*64 + l)*8];
        short8v bl = *(const short8v*)&Bl[(kk*64 + l)*8];
        acc = __builtin_amdgcn_mfma_f32_16x16x32_bf16(ah, bh, acc, 0, 0, 0);
        acc = __builtin_amdgcn_mfma_f32_16x16x32_bf16(al, bh, acc, 0, 0, 0);
        acc = __builtin_amdgcn_mfma_f32_16x16x32_bf16(ah, bl, acc, 0, 0, 0);
      }
      #pragma unroll
      for (int r = 0; r < 4; ++r)            // C/D: col=lane&15, row=quad*4+reg
        Gs[w*256 + (lq*4 + r)*16 + lm] = acc[r];
    } else {
      #pragma unroll
      for (int r = 0; r < 4; ++r)
        Gs[w*256 + (lq*4 + r)*16 + lm] = 0.f;
    }
    __syncthreads();

    // lane (mb, uu): gates at G rows lm, cols g*4 + lq (wave-private tile)
    float gi = Gs[w*256 + lm*16 +  0 + lq] + xq[0];
    float gf = Gs[w*256 + lm*16 +  4 + lq] + xq[1];
    float gg = Gs[w*256 + lm*16 +  8 + lq] + xq[2];
    float go = Gs[w*256 + lm*16 + 12 + lq] + xq[3];
    float c_new = sigf(gf)*c + sigf(gi)*tanhf(gg);
    c = c_new;
    float h = sigf(go)*tanhf(c_new);

    uint hu = __float_as_uint(h);
    float hr = h - __uint_as_float(hu & 0xFFFF0000u);
    hH[(ts & 1)*16384 + mb*256 + uu] = (ushort)(hu >> 16);
    hL[(ts & 1)*16384 + mb*256 + uu] = (ushort)(__float_as_uint(hr) >> 16);
    if (ts == NL-1) hfin[mb*256 + uu] = h;

    xq[0]=xqn[0]; xq[1]=xqn[1]; xq[2]=xqn[2]; xq[3]=xqn[3];
    __threadfence();
    grid.sync();
    __syncthreads();   // Gs reuse guard across steps
  }
}

// ---------------- global mean pool ----------------
__global__ void k_pool(const float* __restrict__ emb, const int* __restrict__ batch,
                       float* __restrict__ gsum, float* __restrict__ gcnt)
{
  __shared__ int bs[256];
  const int t  = threadIdx.x;
  const int n0 = blockIdx.x * 256;
  {
    int n = n0 + t;
    bs[t] = (n < NN) ? batch[n] : -1;
  }
  __syncthreads();
  int cur = bs[0];
  float acc = 0.f; int cnt = 0;
  for (int j = 0; j < 256; ++j){
    int nn = n0 + j;
    if (nn >= NN) break;
    int g = bs[j];
    if (g != cur){
      unsafeAtomicAdd(&gsum[cur*256 + t], acc);
      if (t == 0) unsafeAtomicAdd(&gcnt[cur], (float)cnt);
      acc = 0.f; cnt = 0; cur = g;
    }
    acc += emb[(long long)nn*256 + t];
    ++cnt;
  }
  if (cnt > 0 && cur >= 0){
    unsafeAtomicAdd(&gsum[cur*256 + t], acc);
    if (t == 0) unsafeAtomicAdd(&gcnt[cur], (float)cnt);
  }
}

// ---------------- scorer MLP (pool-finalize + concat fused in) ----------------
__global__ void k_score(const float* __restrict__ gsum, const float* __restrict__ gcnt,
                        const float* __restrict__ hfin, const float* __restrict__ wm1,
                        const float* __restrict__ bm1, const float* __restrict__ wm2,
                        const float* __restrict__ bm2, float* __restrict__ out)
{
  __shared__ float cs[512];
  __shared__ float red[4];
  const int b = blockIdx.x, t = threadIdx.x;
  float inv = 1.0f / fmaxf(gcnt[b], 1.0f);
  cs[t]       = gsum[b*256 + t] * inv;
  cs[256 + t] = hfin[b*256 + t];
  __syncthreads();
  float v = 0.f;
  #pragma unroll 4
  for (int k = 0; k < 512; ++k) v = fmaf(cs[k], wm1[(long long)k*256 + t], v);
  v = fmaxf(v + bm1[t], 0.f) * wm2[t];
  #pragma unroll
  for (int off = 32; off > 0; off >>= 1) v += __shfl_down(v, off, 64);
  if ((t & 63) == 0) red[t >> 6] = v;
  __syncthreads();
  if (t == 0) out[b] = red[0] + red[1] + red[2] + red[3] + bm2[0];
}

} // namespace

extern "C" void kernel_launch(void* const* d_in, const int* in_sizes, int n_in,
                              void* d_out, int out_size, void* d_ws, size_t ws_size,
                              hipStream_t stream)
{
  const float* x     = (const float*)d_in[0];
  const int*   eidx  = (const int*)  d_in[1];
  const int*   batch = (const int*)  d_in[2];
  const int*   paths = (const int*)  d_in[3];
  const float* w1l   = (const float*)d_in[4];
  const float* b1l   = (const float*)d_in[5];
  const float* w1r   = (const float*)d_in[6];
  const float* w2l   = (const float*)d_in[7];
  const float* b2l   = (const float*)d_in[8];
  const float* w2r   = (const float*)d_in[9];
  const float* w_ih  = (const float*)d_in[10];
  const float* w_hh  = (const float*)d_in[11];
  const float* b_ih  = (const float*)d_in[12];
  const float* b_hh  = (const float*)d_in[13];
  const float* wm1   = (const float*)d_in[14];
  const float* bm1   = (const float*)d_in[15];
  const float* wm2   = (const float*)d_in[16];
  const float* bm2   = (const float*)d_in[17];

  const int* src = eidx;        // edge_index[0]
  const int* dst = eidx + NE;   // edge_index[1]

  // workspace layout (floats), offsets multiples of 16 floats
  float* w    = (float*)d_ws;
  float* bufA = w;                         // N*256 (mean agg; layer-2 output in-place)
  float* bufB = bufA + (long long)NN*ND;   // N*256 (h1)
  float* xg   = bufB + (long long)NN*ND;   // 2048*1024 floats
  float* gsum = xg   + 2048*1024;          // 64*256
  float* gcnt = gsum + NB*ND;              // 64
  float* h0   = gcnt + 64;                 // 64*256  (final hidden, fp32)
  ushort* wt1H = (ushort*)(h0 + NB*ND);    // 256*512 each (bf16, fragment-swizzled)
  ushort* wt1L = wt1H + 256*512;
  ushort* wt2H = wt1L + 256*512;
  ushort* wt2L = wt2H + 256*512;
  ushort* hH   = wt2L + 256*512;           // 2*64*256 (LSTM h hi, ping-pong)
  ushort* hL   = hH   + 2*NB*ND;           // 2*64*256

  // CSR scratch aliased into xg region (dead until k_xgate runs, after layer 2)
  int* cnt    = (int*)xg;        // 50432
  int* offs   = cnt    + 50432;  // 50432
  int* cursor = offs   + 50432;  // 50432
  int* bsum   = cursor + 50432;  // 256
  int* bsum2  = bsum   + 256;    // 256
  int* csr    = bsum2  + 256;    // 800000

  // ---- weight prep (fragment-swizzled bf16 hi/lo split) ----
  k_wsplit<<<512, 256, 0, stream>>>(w1l, w1r, wt1H, wt1L);
  k_wsplit<<<512, 256, 0, stream>>>(w2l, w2r, wt2H, wt2L);

  // ---- build CSR (counting sort by dst), shared by both layers ----
  hipMemsetAsync(cnt, 0, 50432*sizeof(int), stream);
  k_hist<<<1024, 256, 0, stream>>>(dst, cnt);
  k_scan_block<<<NSCAN, 256, 0, stream>>>(cnt, offs, bsum);
  k_scan_top<<<1, 256, 0, stream>>>(bsum, bsum2);
  k_scan_add<<<NSCAN, 256, 0, stream>>>(offs, bsum2, cursor);
  k_fill<<<1024, 256, 0, stream>>>(src, dst, cursor, csr);

  // ---- layer 1: gather-mean then MFMA GEMM ----
  k_gather<<<NN, 256, 0, stream>>>(x, offs, csr, bufA);
  k_gemm_mfma<<<(NN+63)/64, 256, 0, stream>>>(bufA, x, wt1H, wt1L, b1l, bufB, 1);

  // ---- layer 2 (node_emb written in-place over bufA) ----
  k_gather<<<NN, 256, 0, stream>>>(bufB, offs, csr, bufA);
  k_gemm_mfma<<<(NN+63)/64, 256, 0, stream>>>(bufA, bufB, wt2H, wt2L, b2l, bufA, 0);

  // ---- global mean pool ----
  hipMemsetAsync(gsum, 0, (NB*ND + 64)*sizeof(float), stream);
  k_pool<<<(NN+255)/256, 256, 0, stream>>>(bufA, batch, gsum, gcnt);

  // ---- LSTM input gates (overwrites the CSR alias region — CSR dead by now) ----
  k_xgate<<<dim3((NB*NL)/64, 1024/256), 256, 0, stream>>>(bufA, paths, w_ih, b_ih, b_hh, xg);

  // ---- LSTM recurrence: single cooperative persistent kernel ----
  {
    const float* xg_c = xg;
    const float* whh_c = w_hh;
    ushort* hH_c = hH; ushort* hL_c = hL; float* h0_c = h0;
    void* args[] = { (void*)&xg_c, (void*)&whh_c, (void*)&hH_c, (void*)&hL_c, (void*)&h0_c };
    hipLaunchCooperativeKernel((const void*)k_lstm, dim3(64), dim3(256), args, 0, stream);
  }

  // ---- fused concat + scorer ----
  k_score<<<NB, 256, 0, stream>>>(gsum, gcnt, h0, wm1, bm1, wm2, bm2, (float*)d_out);
}

// Round 9
// 872.228 us; speedup vs baseline: 1.6641x; 1.6641x over previous
//
#include <hip/hip_runtime.h>

namespace {

constexpr int NN = 50000;   // nodes
constexpr int NE = 800000;  // edges
constexpr int NB = 64;      // graphs / batch
constexpr int NL = 32;      // path length
constexpr int ND = 256;     // D == H == 256
constexpr int NSCAN = 196;  // ceil(50176/256) scan blocks

typedef __attribute__((ext_vector_type(8))) short short8v;  // 8 bf16 (4 VGPRs)
typedef __attribute__((ext_vector_type(4))) float float4v;  // MFMA accumulator

__device__ __forceinline__ float sigf(float x){ return 1.0f/(1.0f + __expf(-x)); }

__device__ __forceinline__ ushort rne_bf16(float f){
  uint u = __float_as_uint(f);
  return (ushort)((u + 0x7FFFu + ((u >> 16) & 1u)) >> 16);
}
__device__ __forceinline__ float bf2f(ushort u){ return __uint_as_float((uint)u << 16); }

// split 8 fp32 -> 8 bf16-hi (truncated; exact bits) + 8 bf16-lo (of remainder)
__device__ __forceinline__ void split8(float4 fa, float4 fb, uint4& h, uint4& lo){
  uint a0=__float_as_uint(fa.x), a1=__float_as_uint(fa.y), a2=__float_as_uint(fa.z), a3=__float_as_uint(fa.w);
  uint b0=__float_as_uint(fb.x), b1=__float_as_uint(fb.y), b2=__float_as_uint(fb.z), b3=__float_as_uint(fb.w);
  h.x = (a0>>16) | (a1 & 0xFFFF0000u);
  h.y = (a2>>16) | (a3 & 0xFFFF0000u);
  h.z = (b0>>16) | (b1 & 0xFFFF0000u);
  h.w = (b2>>16) | (b3 & 0xFFFF0000u);
  float r0 = fa.x - __uint_as_float(a0 & 0xFFFF0000u);
  float r1 = fa.y - __uint_as_float(a1 & 0xFFFF0000u);
  float r2 = fa.z - __uint_as_float(a2 & 0xFFFF0000u);
  float r3 = fa.w - __uint_as_float(a3 & 0xFFFF0000u);
  float r4 = fb.x - __uint_as_float(b0 & 0xFFFF0000u);
  float r5 = fb.y - __uint_as_float(b1 & 0xFFFF0000u);
  float r6 = fb.z - __uint_as_float(b2 & 0xFFFF0000u);
  float r7 = fb.w - __uint_as_float(b3 & 0xFFFF0000u);
  lo.x = (__float_as_uint(r0)>>16) | (__float_as_uint(r1) & 0xFFFF0000u);
  lo.y = (__float_as_uint(r2)>>16) | (__float_as_uint(r3) & 0xFFFF0000u);
  lo.z = (__float_as_uint(r4)>>16) | (__float_as_uint(r5) & 0xFFFF0000u);
  lo.w = (__float_as_uint(r6)>>16) | (__float_as_uint(r7) & 0xFFFF0000u);
}

// ================= CSR build (counting sort of edges by dst) =================
__global__ void k_hist(const int* __restrict__ dst, int* __restrict__ cnt){
  int stride = gridDim.x * blockDim.x;
  for (int e = blockIdx.x*blockDim.x + threadIdx.x; e < NE; e += stride)
    atomicAdd(&cnt[dst[e]], 1);
}

__global__ void k_scan_block(const int* __restrict__ cnt, int* __restrict__ offs,
                             int* __restrict__ bsum){
  __shared__ int s[256];
  const int t = threadIdx.x, i = blockIdx.x*256 + t;
  int v = cnt[i];
  s[t] = v; __syncthreads();
  #pragma unroll
  for (int off = 1; off < 256; off <<= 1){
    int x = (t >= off) ? s[t-off] : 0;
    __syncthreads();
    s[t] += x;
    __syncthreads();
  }
  offs[i] = s[t] - v;
  if (t == 255) bsum[blockIdx.x] = s[255];
}

__global__ void k_scan_top(const int* __restrict__ bsum, int* __restrict__ bsum2){
  __shared__ int s[256];
  const int t = threadIdx.x;
  int v = (t < NSCAN) ? bsum[t] : 0;
  s[t] = v; __syncthreads();
  #pragma unroll
  for (int off = 1; off < 256; off <<= 1){
    int x = (t >= off) ? s[t-off] : 0;
    __syncthreads();
    s[t] += x;
    __syncthreads();
  }
  if (t < NSCAN) bsum2[t] = s[t] - v;
}

__global__ void k_scan_add(int* __restrict__ offs, const int* __restrict__ bsum2,
                           int* __restrict__ cursor){
  const int i = blockIdx.x*256 + threadIdx.x;
  int v = offs[i] + bsum2[blockIdx.x];
  offs[i] = v;
  cursor[i] = v;
}

__global__ void k_fill(const int* __restrict__ src, const int* __restrict__ dst,
                       int* __restrict__ cursor, int* __restrict__ csr){
  int stride = gridDim.x * blockDim.x;
  for (int e = blockIdx.x*blockDim.x + threadIdx.x; e < NE; e += stride){
    int d = dst[e];
    int pos = atomicAdd(&cursor[d], 1);
    csr[pos] = src[e];
  }
}

// ================= fp32 -> bf16 (RNE) bulk convert =================
__global__ void k_tobf16(const float* __restrict__ in, ushort* __restrict__ out){
  const int i = blockIdx.x*blockDim.x + threadIdx.x;   // one per 8 elems
  const float4 a = ((const float4*)in)[i*2];
  const float4 b = ((const float4*)in)[i*2+1];
  ushort o[8] = { rne_bf16(a.x), rne_bf16(a.y), rne_bf16(a.z), rne_bf16(a.w),
                  rne_bf16(b.x), rne_bf16(b.y), rne_bf16(b.z), rne_bf16(b.w) };
  ((uint4*)out)[i] = *(uint4*)o;
}

// ================= mean-aggregate gather over bf16 features =================
// Wave per edge-row: lane l loads ushort4 (8B) at feat[src*256 + l*4] -> one 512B row
// per instruction. fp32 accumulate; cross-wave reduce via LDS; coalesced 1KB store.
__launch_bounds__(256, 8)
__global__ void k_gather_bf16(const ushort* __restrict__ feat, const int* __restrict__ offs,
                              const int* __restrict__ csr, float* __restrict__ out){
  __shared__ float4 sp[256];
  const int u = blockIdx.x, t = threadIdx.x;
  const int w = t >> 6, l = t & 63;
  const int beg = offs[u], end = offs[u+1];
  const int lc = l * 4;
  float a0 = 0.f, a1 = 0.f, a2 = 0.f, a3 = 0.f;
  int e = beg + w;
  for (; e + 4 < end; e += 8){
    int s0 = csr[e], s1 = csr[e+4];
    ushort4 v0 = *(const ushort4*)(feat + (long long)s0*ND + lc);
    ushort4 v1 = *(const ushort4*)(feat + (long long)s1*ND + lc);
    a0 += bf2f(v0.x) + bf2f(v1.x);
    a1 += bf2f(v0.y) + bf2f(v1.y);
    a2 += bf2f(v0.z) + bf2f(v1.z);
    a3 += bf2f(v0.w) + bf2f(v1.w);
  }
  if (e < end){
    int s0 = csr[e];
    ushort4 v0 = *(const ushort4*)(feat + (long long)s0*ND + lc);
    a0 += bf2f(v0.x); a1 += bf2f(v0.y); a2 += bf2f(v0.z); a3 += bf2f(v0.w);
  }
  sp[t] = make_float4(a0, a1, a2, a3);
  __syncthreads();
  if (t < 64){
    float4 p0 = sp[t], p1 = sp[64+t], p2 = sp[128+t], p3 = sp[192+t];
    float inv = 1.0f / fmaxf((float)(end - beg), 1.0f);
    float4 r;
    r.x = (p0.x + p1.x + p2.x + p3.x) * inv;
    r.y = (p0.y + p1.y + p2.y + p3.y) * inv;
    r.z = (p0.z + p1.z + p2.z + p3.z) * inv;
    r.w = (p0.w + p1.w + p2.w + p3.w) * inv;
    *(float4*)(out + (long long)u*ND + t*4) = r;
  }
}

// ============ weight prep: fragment-linear swizzled [wl; wr] bf16 hi/lo ============
__global__ void k_wsplit(const float* __restrict__ wl, const float* __restrict__ wr,
                         ushort* __restrict__ WtH, ushort* __restrict__ WtL){
  const int k = blockIdx.x;    // 0..511
  const int n = threadIdx.x;   // 0..255
  float v = (k < 256) ? wl[k*256 + n] : wr[(k-256)*256 + n];
  uint u = __float_as_uint(v);
  float r = v - __uint_as_float(u & 0xFFFF0000u);
  const int wc = n >> 6, nt = (n >> 4) & 3, lm = n & 15;
  const int kk = k >> 5, lq = (k >> 3) & 3, j = k & 7;
  const long long idx = (long long)(((wc*4 + nt)*16 + kk)*64 + lq*16 + lm)*8 + j;
  WtH[idx] = (ushort)(u >> 16);
  WtL[idx] = (ushort)(__float_as_uint(r) >> 16);
}

// ============ MFMA SAGE GEMM: barrier-free main loop + distance-1 prefetch ============
// Optional Cb: also write C as bf16 (RNE) — feeds the next layer's gather.
__launch_bounds__(256, 2)
__global__ void k_gemm_mfma(const float* __restrict__ A1, const float* __restrict__ A2,
                            const ushort* __restrict__ WtH, const ushort* __restrict__ WtL,
                            const float* __restrict__ bias, float* __restrict__ C,
                            ushort* __restrict__ Cb, int relu)
{
  __shared__ float eb[16*260];     // epilogue staging (16.6 KB)
  const int t  = threadIdx.x;
  const int w  = t >> 6;           // wave 0..3
  const int l  = t & 63;           // lane
  const int lm = l & 15;
  const int lq = l >> 4;
  const int m0 = blockIdx.x * 64;

  const uint4* BH4 = (const uint4*)WtH;
  const uint4* BL4 = (const uint4*)WtL;

  const float4v vzero = {0.f, 0.f, 0.f, 0.f};
  float4v acc[4][4];
  #pragma unroll
  for (int i = 0; i < 4; ++i)
    #pragma unroll
    for (int j = 0; j < 4; ++j) acc[i][j] = vzero;

  long long arow[4];
  #pragma unroll
  for (int mt = 0; mt < 4; ++mt){
    int row = m0 + mt*16 + lm;
    row = (row < NN) ? row : (NN - 1);          // clamp: branchless, dup rows discarded later
    arow[mt] = (long long)row * ND;
  }
  int bbase[4];
  #pragma unroll
  for (int nt = 0; nt < 4; ++nt) bbase[nt] = (w*4 + nt)*1024 + l;

  auto ldB = [&](int kk, uint4* bh, uint4* bl){
    #pragma unroll
    for (int nt = 0; nt < 4; ++nt){
      int idx = bbase[nt] + kk*64;
      bh[nt] = BH4[idx];
      bl[nt] = BL4[idx];
    }
  };
  auto ldA = [&](int kk, uint4* ah, uint4* al){
    const float* Ab = (kk < 8) ? A1 : A2;       // constant-folds under full unroll
    const int koff = (kk & 7)*32 + lq*8;
    #pragma unroll
    for (int mt = 0; mt < 4; ++mt){
      const float* p = Ab + arow[mt] + koff;
      float4 fa = *(const float4*)p;
      float4 fb = *(const float4*)(p + 4);
      split8(fa, fb, ah[mt], al[mt]);
    }
  };

  uint4 bhb[2][4], blb[2][4], ahb[2][4], alb[2][4];
  ldB(0, bhb[0], blb[0]);
  ldA(0, ahb[0], alb[0]);

  #pragma unroll
  for (int kk = 0; kk < 16; ++kk){
    const int cur = kk & 1, nx = cur ^ 1;
    if (kk < 15){                               // constant under unroll
      ldB(kk + 1, bhb[nx], blb[nx]);
      ldA(kk + 1, ahb[nx], alb[nx]);
    }
    #pragma unroll
    for (int nt = 0; nt < 4; ++nt){
      short8v bh = *(short8v*)&bhb[cur][nt];
      short8v bl = *(short8v*)&blb[cur][nt];
      #pragma unroll
      for (int mt = 0; mt < 4; ++mt){
        short8v ah = *(short8v*)&ahb[cur][mt];
        short8v al = *(short8v*)&alb[cur][mt];
        acc[mt][nt] = __builtin_amdgcn_mfma_f32_16x16x32_bf16(ah, bh, acc[mt][nt], 0, 0, 0);
        acc[mt][nt] = __builtin_amdgcn_mfma_f32_16x16x32_bf16(al, bh, acc[mt][nt], 0, 0, 0);
        acc[mt][nt] = __builtin_amdgcn_mfma_f32_16x16x32_bf16(ah, bl, acc[mt][nt], 0, 0, 0);
      }
    }
  }

  // ---- epilogue: LDS transpose per 16-row slab, coalesced float4 stores ----
  float bvv[4];
  #pragma unroll
  for (int nt = 0; nt < 4; ++nt) bvv[nt] = bias[w*64 + nt*16 + lm];

  #pragma unroll
  for (int mt = 0; mt < 4; ++mt){
    #pragma unroll
    for (int nt = 0; nt < 4; ++nt){
      #pragma unroll
      for (int r = 0; r < 4; ++r){
        float v = acc[mt][nt][r] + bvv[nt];
        if (relu) v = fmaxf(v, 0.f);
        eb[(lq*4 + r)*260 + w*64 + nt*16 + lm] = v;   // C/D: col=lane&15, row=quad*4+reg
      }
    }
    __syncthreads();
    #pragma unroll
    for (int i = 0; i < 4; ++i){
      int idx = i*256 + t;           // 0..1023
      int rr  = idx >> 6;            // 0..15
      int c4  = (idx & 63) * 4;      // 0..252
      int grow = m0 + mt*16 + rr;
      if (grow < NN){
        float4 fv = *(float4*)&eb[rr*260 + c4];
        *(float4*)(C + (long long)grow*ND + c4) = fv;
        if (Cb){
          ushort ub[4] = { rne_bf16(fv.x), rne_bf16(fv.y), rne_bf16(fv.z), rne_bf16(fv.w) };
          *(ushort4*)(Cb + (long long)grow*ND + c4) = *(ushort4*)ub;
        }
      }
    }
    __syncthreads();
  }
}

// ---------------- LSTM input gates: Xg[i][g] = emb[paths[i]] . w_ih[g] + b_ih[g]+b_hh[g] ----------------
__launch_bounds__(256, 3)
__global__ void k_xgate(const float* __restrict__ emb, const int* __restrict__ paths,
                        const float* __restrict__ w_ih, const float* __restrict__ b_ih,
                        const float* __restrict__ b_hh, float* __restrict__ xg)
{
  __shared__ float As[16][68];
  __shared__ float Ws[16][260];
  const int t  = threadIdx.x;
  const int m0 = blockIdx.x * 64;    // path rows (2048 total)
  const int g0 = blockIdx.y * 256;   // gate cols (1024 total)
  const int rg = t >> 5, cg = t & 31;
  const int sm = t >> 2, sj = (t & 3) * 4;

  float acc[8][8];
  #pragma unroll
  for (int i = 0; i < 8; ++i)
    #pragma unroll
    for (int j = 0; j < 8; ++j) acc[i][j] = 0.f;

  const int node = paths[m0 + sm];
  const float* arow = emb  + (long long)node*ND;
  const float* wrow = w_ih + (long long)(g0 + t)*ND;

  for (int k0 = 0; k0 < 256; k0 += 16){
    float4 av = *(const float4*)(arow + k0 + sj);
    float4 q0 = *(const float4*)(wrow + k0 + 0);
    float4 q1 = *(const float4*)(wrow + k0 + 4);
    float4 q2 = *(const float4*)(wrow + k0 + 8);
    float4 q3 = *(const float4*)(wrow + k0 + 12);
    __syncthreads();
    As[sj+0][sm]=av.x; As[sj+1][sm]=av.y; As[sj+2][sm]=av.z; As[sj+3][sm]=av.w;
    Ws[ 0][t]=q0.x; Ws[ 1][t]=q0.y; Ws[ 2][t]=q0.z; Ws[ 3][t]=q0.w;
    Ws[ 4][t]=q1.x; Ws[ 5][t]=q1.y; Ws[ 6][t]=q1.z; Ws[ 7][t]=q1.w;
    Ws[ 8][t]=q2.x; Ws[ 9][t]=q2.y; Ws[10][t]=q2.z; Ws[11][t]=q2.w;
    Ws[12][t]=q3.x; Ws[13][t]=q3.y; Ws[14][t]=q3.z; Ws[15][t]=q3.w;
    __syncthreads();
    #pragma unroll
    for (int k = 0; k < 16; ++k){
      float a[8], b[8];
      *(float4*)&a[0] = *(const float4*)&As[k][rg*8];
      *(float4*)&a[4] = *(const float4*)&As[k][rg*8+4];
      *(float4*)&b[0] = *(const float4*)&Ws[k][cg*8];
      *(float4*)&b[4] = *(const float4*)&Ws[k][cg*8+4];
      #pragma unroll
      for (int i = 0; i < 8; ++i)
        #pragma unroll
        for (int j = 0; j < 8; ++j)
          acc[i][j] = fmaf(a[i], b[j], acc[i][j]);
    }
  }

  float bv[8];
  #pragma unroll
  for (int j = 0; j < 8; ++j){ int g = g0 + cg*8 + j; bv[j] = b_ih[g] + b_hh[g]; }
  #pragma unroll
  for (int i = 0; i < 8; ++i){
    int row = m0 + rg*8 + i;
    float o[8];
    #pragma unroll
    for (int j = 0; j < 8; ++j) o[j] = acc[i][j] + bv[j];
    *(float4*)(xg + (long long)row*1024 + g0 + cg*8 + 0) = *(float4*)&o[0];
    *(float4*)(xg + (long long)row*1024 + g0 + cg*8 + 4) = *(float4*)&o[4];
  }
}

// ---------------- one LSTM step (32-launch version; grid.sync measured 5x worse) ----------------
__launch_bounds__(256, 4)
__global__ void k_lstm_step(const float* __restrict__ h_in, float* __restrict__ h_out,
                            float* __restrict__ c_state, const float* __restrict__ xg,
                            const float* __restrict__ w_hh, int tstep)
{
  __shared__ float ws[4*256];
  __shared__ float hs[32*260];
  __shared__ float part[2*128];
  __shared__ float gs[128];
  const int t  = threadIdx.x;
  const int u  = blockIdx.x >> 1;
  const int b0 = (blockIdx.x & 1) * 32;

  {
    int gate = t >> 6, c4 = (t & 63) * 4;
    float4 v = *(const float4*)(w_hh + (long long)(gate*256 + u)*256 + c4);
    *(float4*)&ws[gate*256 + c4] = v;
  }
  #pragma unroll
  for (int i = 0; i < 8; ++i){
    int idx = i*256 + t;
    int b = idx >> 6, c4 = (idx & 63) * 4;
    float4 v = *(const float4*)(h_in + (long long)(b0 + b)*256 + c4);
    *(float4*)&hs[b*260 + c4] = v;
  }
  __syncthreads();

  const int b  = t & 31;
  const int g  = (t >> 5) & 3;
  const int kd = t >> 7;
  float s = 0.f;
  const float* hp = &hs[b*260 + kd*128];
  const float* wp = &ws[g*256 + kd*128];
  #pragma unroll
  for (int k4 = 0; k4 < 32; ++k4){
    float4 h4 = *(const float4*)(hp + k4*4);
    float4 w4 = *(const float4*)(wp + k4*4);
    s += h4.x*w4.x + h4.y*w4.y + h4.z*w4.z + h4.w*w4.w;
  }
  part[kd*128 + b*4 + g] = s;
  __syncthreads();

  if (t < 128){
    int bb = t >> 2, gg = t & 3;
    const float* xp = xg + ((long long)(b0 + bb)*NL + tstep)*1024;
    gs[t] = part[t] + part[128 + t] + xp[gg*256 + u];
  }
  __syncthreads();

  if (t < 32){
    float gi = gs[t*4+0], gf = gs[t*4+1], gG = gs[t*4+2], go = gs[t*4+3];
    int bb = b0 + t;
    float c_old = c_state[bb*256 + u];
    float c_new = sigf(gf)*c_old + sigf(gi)*tanhf(gG);
    c_state[bb*256 + u] = c_new;
    h_out[bb*256 + u] = sigf(go)*tanhf(c_new);
  }
}

// ---------------- global mean pool ----------------
__global__ void k_pool(const float* __restrict__ emb, const int* __restrict__ batch,
                       float* __restrict__ gsum, float* __restrict__ gcnt)
{
  __shared__ int bs[256];
  const int t  = threadIdx.x;
  const int n0 = blockIdx.x * 256;
  {
    int n = n0 + t;
    bs[t] = (n < NN) ? batch[n] : -1;
  }
  __syncthreads();
  int cur = bs[0];
  float acc = 0.f; int cnt = 0;
  for (int j = 0; j < 256; ++j){
    int nn = n0 + j;
    if (nn >= NN) break;
    int g = bs[j];
    if (g != cur){
      unsafeAtomicAdd(&gsum[cur*256 + t], acc);
      if (t == 0) unsafeAtomicAdd(&gcnt[cur], (float)cnt);
      acc = 0.f; cnt = 0; cur = g;
    }
    acc += emb[(long long)nn*256 + t];
    ++cnt;
  }
  if (cnt > 0 && cur >= 0){
    unsafeAtomicAdd(&gsum[cur*256 + t], acc);
    if (t == 0) unsafeAtomicAdd(&gcnt[cur], (float)cnt);
  }
}

// ---------------- scorer MLP (pool-finalize + concat fused in) ----------------
__global__ void k_score(const float* __restrict__ gsum, const float* __restrict__ gcnt,
                        const float* __restrict__ hfin, const float* __restrict__ wm1,
                        const float* __restrict__ bm1, const float* __restrict__ wm2,
                        const float* __restrict__ bm2, float* __restrict__ out)
{
  __shared__ float cs[512];
  __shared__ float red[4];
  const int b = blockIdx.x, t = threadIdx.x;
  float inv = 1.0f / fmaxf(gcnt[b], 1.0f);
  cs[t]       = gsum[b*256 + t] * inv;
  cs[256 + t] = hfin[b*256 + t];
  __syncthreads();
  float v = 0.f;
  #pragma unroll 4
  for (int k = 0; k < 512; ++k) v = fmaf(cs[k], wm1[(long long)k*256 + t], v);
  v = fmaxf(v + bm1[t], 0.f) * wm2[t];
  #pragma unroll
  for (int off = 32; off > 0; off >>= 1) v += __shfl_down(v, off, 64);
  if ((t & 63) == 0) red[t >> 6] = v;
  __syncthreads();
  if (t == 0) out[b] = red[0] + red[1] + red[2] + red[3] + bm2[0];
}

} // namespace

extern "C" void kernel_launch(void* const* d_in, const int* in_sizes, int n_in,
                              void* d_out, int out_size, void* d_ws, size_t ws_size,
                              hipStream_t stream)
{
  const float* x     = (const float*)d_in[0];
  const int*   eidx  = (const int*)  d_in[1];
  const int*   batch = (const int*)  d_in[2];
  const int*   paths = (const int*)  d_in[3];
  const float* w1l   = (const float*)d_in[4];
  const float* b1l   = (const float*)d_in[5];
  const float* w1r   = (const float*)d_in[6];
  const float* w2l   = (const float*)d_in[7];
  const float* b2l   = (const float*)d_in[8];
  const float* w2r   = (const float*)d_in[9];
  const float* w_ih  = (const float*)d_in[10];
  const float* w_hh  = (const float*)d_in[11];
  const float* b_ih  = (const float*)d_in[12];
  const float* b_hh  = (const float*)d_in[13];
  const float* wm1   = (const float*)d_in[14];
  const float* bm1   = (const float*)d_in[15];
  const float* wm2   = (const float*)d_in[16];
  const float* bm2   = (const float*)d_in[17];

  const int* src = eidx;        // edge_index[0]
  const int* dst = eidx + NE;   // edge_index[1]

  // workspace layout (floats), offsets multiples of 16 floats
  float* w    = (float*)d_ws;
  float* bufA = w;                         // N*256 (mean agg; layer-2 output in-place)
  float* bufB = bufA + (long long)NN*ND;   // N*256 (h1 fp32)
  float* xg   = bufB + (long long)NN*ND;   // 2048*1024 floats
  float* gsum = xg   + 2048*1024;          // 64*256
  float* gcnt = gsum + NB*ND;              // 64
  float* h0   = gcnt + 64;                 // 64*256
  float* c0   = h0   + NB*ND;              // 64*256
  float* h1   = c0   + NB*ND;              // 64*256
  ushort* wt1H = (ushort*)(h1 + NB*ND);    // 256*512 each (bf16, fragment-swizzled)
  ushort* wt1L = wt1H + 256*512;
  ushort* wt2H = wt1L + 256*512;
  ushort* wt2L = wt2H + 256*512;
  ushort* fb16 = wt2L + 256*512;           // N*256 bf16 (x copy, then h1 copy — never both live)

  // CSR scratch aliased into xg region (dead until k_xgate runs, after layer 2)
  int* cnt    = (int*)xg;        // 50432
  int* offs   = cnt    + 50432;  // 50432
  int* cursor = offs   + 50432;  // 50432
  int* bsum   = cursor + 50432;  // 256
  int* bsum2  = bsum   + 256;    // 256
  int* csr    = bsum2  + 256;    // 800000

  // ---- weight prep (fragment-swizzled bf16 hi/lo split) ----
  k_wsplit<<<512, 256, 0, stream>>>(w1l, w1r, wt1H, wt1L);
  k_wsplit<<<512, 256, 0, stream>>>(w2l, w2r, wt2H, wt2L);

  // ---- x -> bf16 copy for the mean-agg path ----
  k_tobf16<<<(NN*ND/8 + 255)/256, 256, 0, stream>>>(x, fb16);

  // ---- build CSR (counting sort by dst), shared by both layers ----
  hipMemsetAsync(cnt, 0, 50432*sizeof(int), stream);
  k_hist<<<1024, 256, 0, stream>>>(dst, cnt);
  k_scan_block<<<NSCAN, 256, 0, stream>>>(cnt, offs, bsum);
  k_scan_top<<<1, 256, 0, stream>>>(bsum, bsum2);
  k_scan_add<<<NSCAN, 256, 0, stream>>>(offs, bsum2, cursor);
  k_fill<<<1024, 256, 0, stream>>>(src, dst, cursor, csr);

  // ---- layer 1: bf16 gather-mean, then MFMA GEMM (dual-writes h1 fp32 + bf16) ----
  k_gather_bf16<<<NN, 256, 0, stream>>>(fb16, offs, csr, bufA);
  k_gemm_mfma<<<(NN+63)/64, 256, 0, stream>>>(bufA, x, wt1H, wt1L, b1l, bufB, fb16, 1);

  // ---- layer 2 (node_emb written in-place over bufA) ----
  k_gather_bf16<<<NN, 256, 0, stream>>>(fb16, offs, csr, bufA);
  k_gemm_mfma<<<(NN+63)/64, 256, 0, stream>>>(bufA, bufB, wt2H, wt2L, b2l, bufA, (ushort*)nullptr, 0);

  // ---- global mean pool ----
  hipMemsetAsync(gsum, 0, (NB*ND + 64)*sizeof(float), stream);
  k_pool<<<(NN+255)/256, 256, 0, stream>>>(bufA, batch, gsum, gcnt);

  // ---- LSTM input gates (overwrites the CSR alias region — CSR dead by now) ----
  k_xgate<<<dim3((NB*NL)/64, 1024/256), 256, 0, stream>>>(bufA, paths, w_ih, b_ih, b_hh, xg);

  // ---- LSTM recurrence: 32 launches, ping-pong h buffers ----
  hipMemsetAsync(h0, 0, 2*(size_t)NB*ND*sizeof(float), stream);  // h0 + c0
  for (int ts = 0; ts < NL; ++ts){
    float* hin  = (ts & 1) ? h1 : h0;
    float* hout = (ts & 1) ? h0 : h1;
    k_lstm_step<<<512, 256, 0, stream>>>(hin, hout, c0, xg, w_hh, ts);
  }
  // ts=31 wrote h0 -> final hidden state

  // ---- fused concat + scorer ----
  k_score<<<NB, 256, 0, stream>>>(gsum, gcnt, h0, wm1, bm1, wm2, bm2, (float*)d_out);
}